// Round 4
// baseline (559.066 us; speedup 1.0000x reference)
//
#include <hip/hip_runtime.h>

// AttnBlock B=32, C=512, N=1024. All GEMMs via bf16 MFMA 16x16x32.
// Layouts: h[b][n][c], q[b][n][c], k[b][n][c], v[b][c][n], O[b][n][c].
// Attention is fused flash-style (no S materialization, no-max softmax).

#define C_DIM 512
#define N_PIX 1024
#define BATCH 32
#define CPG 16
#define EPS 1e-6f
#define SCALE 0.044194173824159216f  // 512^-0.5
#define ESTRIDE 66                   // epilogue LDS row stride (floats)
#define PSTRIDE 136                  // flash P LDS row stride (u16)

typedef unsigned short u16;
typedef __attribute__((ext_vector_type(8))) short bf16x8;
typedef __attribute__((ext_vector_type(4))) float f32x4;
typedef __attribute__((ext_vector_type(2))) float f32x2;

static __device__ __forceinline__ float bf2f(u16 u) {
    union { unsigned int i; float f; } v; v.i = ((unsigned int)u) << 16; return v.f;
}
static __device__ __forceinline__ u16 f2bf(float f) {
    union { float f; unsigned int i; } v; v.f = f;
    unsigned int r = v.i + 0x7fffu + ((v.i >> 16) & 1u);
    return (u16)(r >> 16);
}

static __device__ __forceinline__ void gl_lds16(const u16* g, u16* l) {
    __builtin_amdgcn_global_load_lds(
        (const __attribute__((address_space(1))) unsigned int*)g,
        (__attribute__((address_space(3))) unsigned int*)l,
        16, 0, 0);
}

// ------------------------------------------------------------- weights->bf16
__global__ __launch_bounds__(256) void wconv_kernel(
        const float* __restrict__ wq, const float* __restrict__ wk,
        const float* __restrict__ wv, const float* __restrict__ wp,
        u16* __restrict__ out) {
    int i = blockIdx.x * 256 + threadIdx.x;
    int mat = i >> 16;
    const float* src = (mat == 0) ? wq : (mat == 1) ? wk : (mat == 2) ? wv : wp;
    float4 v = ((const float4*)src)[i & 65535];
    ushort4 o;
    o.x = f2bf(v.x); o.y = f2bf(v.y); o.z = f2bf(v.z); o.w = f2bf(v.w);
    *(ushort4*)&out[(size_t)i * 4] = o;
}

// ------------------------------------------------------------- GroupNorm
__global__ __launch_bounds__(256) void gn_kernel(
        const float* __restrict__ x, const float* __restrict__ gw,
        const float* __restrict__ gb, u16* __restrict__ h) {
    int blk = blockIdx.x;
    int b = blk >> 5, g = blk & 31;
    size_t base = ((size_t)(b * C_DIM + g * CPG)) * N_PIX;
    const float4* xv = (const float4*)(x + base);
    int tid = threadIdx.x;

    float s = 0.f, sq = 0.f;
    for (int i = tid; i < (CPG * N_PIX) / 4; i += 256) {
        float4 v = xv[i];
        s  += v.x + v.y + v.z + v.w;
        sq += v.x * v.x + v.y * v.y + v.z * v.z + v.w * v.w;
    }
    __shared__ float rs[256], rq[256];
    rs[tid] = s; rq[tid] = sq;
    __syncthreads();
    for (int off = 128; off > 0; off >>= 1) {
        if (tid < off) { rs[tid] += rs[tid + off]; rq[tid] += rq[tid + off]; }
        __syncthreads();
    }
    float mean = rs[0] * (1.0f / (CPG * N_PIX));
    float var  = rq[0] * (1.0f / (CPG * N_PIX)) - mean * mean;
    float inv  = rsqrtf(var + EPS);

    __shared__ u16 Ls[CPG * N_PIX];
    for (int i = tid; i < (CPG * N_PIX) / 4; i += 256) {
        int c_local = i >> 8;
        int c = g * CPG + c_local;
        float sc = gw[c] * inv;
        float sh = gb[c] - mean * sc;
        float4 v = xv[i];
        ushort4 o;
        o.x = f2bf(v.x * sc + sh); o.y = f2bf(v.y * sc + sh);
        o.z = f2bf(v.z * sc + sh); o.w = f2bf(v.w * sc + sh);
        *(ushort4*)&Ls[c_local * N_PIX + (i & 255) * 4] = o;
    }
    __syncthreads();
    u16* hb = h + (size_t)b * N_PIX * C_DIM + g * CPG;
    for (int n = tid; n < N_PIX; n += 256) {
        unsigned int pk[8];
#pragma unroll
        for (int j = 0; j < 8; ++j) {
            unsigned int lo = Ls[(2 * j) * N_PIX + n];
            unsigned int hi = Ls[(2 * j + 1) * N_PIX + n];
            pk[j] = lo | (hi << 16);
        }
        uint4* dst = (uint4*)(hb + (size_t)n * C_DIM);
        dst[0] = make_uint4(pk[0], pk[1], pk[2], pk[3]);
        dst[1] = make_uint4(pk[4], pk[5], pk[6], pk[7]);
    }
}

// ------------------------------------------------------------- merged q+k
// q[n][o], k[n][o] = h[n][c]*W[o][c] + b[o]; one A staging, dual acc.
// grid (4=oT, 8=nT, 32=b), 256 thr.
__global__ __launch_bounds__(256) void qk_kernel(
        const u16* __restrict__ h, const u16* __restrict__ wqk,
        const float* __restrict__ bq, const float* __restrict__ bk,
        u16* __restrict__ q, u16* __restrict__ k) {
    int bx = blockIdx.x, by = blockIdx.y, b = blockIdx.z;
    const u16* gA = h + (size_t)b * 524288 + (size_t)by * 128 * 512;
    const u16* gQ = wqk + (size_t)bx * 128 * 512;
    const u16* gK = gQ + 262144;

    __shared__ __align__(16) u16 smem[24576];      // 48 KB
    u16* As = smem;
    u16* Qs = smem + 8192;
    u16* Ks = smem + 16384;

    int tid = threadIdx.x;
    int lane = tid & 63, wave = tid >> 6;
    int wm = wave >> 1, wn = wave & 1;
    int quad = lane >> 4, l15 = lane & 15, l7 = lane & 7;

    int srow = tid >> 3;
    int lg = (tid & 7) ^ (srow & 7);
    const u16* pA = gA + (size_t)srow * 512 + lg * 8;
    const u16* pQ = gQ + (size_t)srow * 512 + lg * 8;
    const u16* pK = gK + (size_t)srow * 512 + lg * 8;
    u16* lA = As + tid * 8;
    u16* lQ = Qs + tid * 8;
    u16* lK = Ks + tid * 8;

    f32x4 accq[4][4], acck[4][4];
#pragma unroll
    for (int mt = 0; mt < 4; ++mt)
#pragma unroll
        for (int nt = 0; nt < 4; ++nt) {
            accq[mt][nt] = (f32x4){0.f, 0.f, 0.f, 0.f};
            acck[mt][nt] = (f32x4){0.f, 0.f, 0.f, 0.f};
        }

    for (int k0 = 0; k0 < 512; k0 += 64) {
#pragma unroll
        for (int r = 0; r < 4; ++r) {
            gl_lds16(pA + (size_t)r * 32 * 512 + k0, lA + r * 2048);
            gl_lds16(pQ + (size_t)r * 32 * 512 + k0, lQ + r * 2048);
            gl_lds16(pK + (size_t)r * 32 * 512 + k0, lK + r * 2048);
        }
        __syncthreads();
#pragma unroll
        for (int ks = 0; ks < 2; ++ks) {
            bf16x8 af[4], fq[4], fk[4];
            int gr_ = ((ks * 4 + quad) ^ l7) * 8;
#pragma unroll
            for (int t = 0; t < 4; ++t) {
                af[t] = *(const bf16x8*)&As[(wm * 64 + t * 16 + l15) * 64 + gr_];
                fq[t] = *(const bf16x8*)&Qs[(wn * 64 + t * 16 + l15) * 64 + gr_];
                fk[t] = *(const bf16x8*)&Ks[(wn * 64 + t * 16 + l15) * 64 + gr_];
            }
#pragma unroll
            for (int mt = 0; mt < 4; ++mt)
#pragma unroll
                for (int nt = 0; nt < 4; ++nt) {
                    accq[mt][nt] = __builtin_amdgcn_mfma_f32_16x16x32_bf16(
                        af[mt], fq[nt], accq[mt][nt], 0, 0, 0);
                    acck[mt][nt] = __builtin_amdgcn_mfma_f32_16x16x32_bf16(
                        af[mt], fk[nt], acck[mt][nt], 0, 0, 0);
                }
        }
        __syncthreads();
    }

    float* ebw = (float*)smem + wave * (16 * ESTRIDE);
    int er = lane >> 4, ec4 = (lane & 15) * 4;
#pragma unroll
    for (int outm = 0; outm < 2; ++outm) {
        u16* out = outm ? k : q;
        const float* bi = outm ? bk : bq;
#pragma unroll
        for (int mt = 0; mt < 4; ++mt) {
#pragma unroll
            for (int nt = 0; nt < 4; ++nt) {
                f32x4 a = outm ? acck[mt][nt] : accq[mt][nt];
#pragma unroll
                for (int reg = 0; reg < 4; ++reg)
                    ebw[(quad * 4 + reg) * ESTRIDE + nt * 16 + l15] = a[reg];
            }
#pragma unroll
            for (int j2 = 0; j2 < 4; ++j2) {
                int lr = er + 4 * j2;
                f32x2 v0 = *(f32x2*)&ebw[lr * ESTRIDE + ec4];
                f32x2 v1 = *(f32x2*)&ebw[lr * ESTRIDE + ec4 + 2];
                int gr = by * 128 + wm * 64 + mt * 16 + lr;
                int gc = bx * 128 + wn * 64 + ec4;
                float4 b4 = *(const float4*)&bi[gc];
                ushort4 st;
                st.x = f2bf(v0.x + b4.x); st.y = f2bf(v0.y + b4.y);
                st.z = f2bf(v1.x + b4.z); st.w = f2bf(v1.y + b4.w);
                *(ushort4*)&out[(size_t)b * 524288 + (size_t)gr * 512 + gc] = st;
            }
        }
    }
}

// ------------------------------------------------------------- MFMA GEMM
// MODE 1: v, bf16 out +bias[row]; MODE 4: proj, f32 out +bias[row]+resid
template <int MODE>
__global__ __launch_bounds__(256) void gemm_kernel(
        const u16* __restrict__ A, const u16* __restrict__ B,
        void* __restrict__ Cv, const float* __restrict__ bias,
        const float* __restrict__ xres, int K,
        int rsA, int rsB, int rsC,
        long long bsA, long long bsB, long long bsC) {
    int bx = blockIdx.x, by = blockIdx.y, b = blockIdx.z;
    const u16* gA = A + (size_t)b * bsA + (size_t)by * 128 * rsA;
    const u16* gB = B + (size_t)b * bsB + (size_t)bx * 128 * rsB;

    __shared__ __align__(16) u16 smem[16384];
    u16* As = smem;
    u16* Bs = smem + 8192;

    int tid = threadIdx.x;
    int lane = tid & 63, wave = tid >> 6;
    int wm = wave >> 1, wn = wave & 1;
    int quad = lane >> 4, l15 = lane & 15, l7 = lane & 7;

    int srow = tid >> 3;
    int lg = (tid & 7) ^ (srow & 7);
    const u16* pA = gA + (size_t)srow * rsA + lg * 8;
    const u16* pB = gB + (size_t)srow * rsB + lg * 8;
    u16* lA = As + tid * 8;
    u16* lB = Bs + tid * 8;

    f32x4 acc[4][4];
#pragma unroll
    for (int mt = 0; mt < 4; ++mt)
#pragma unroll
        for (int nt = 0; nt < 4; ++nt)
            acc[mt][nt] = (f32x4){0.f, 0.f, 0.f, 0.f};

    for (int k0 = 0; k0 < K; k0 += 64) {
#pragma unroll
        for (int r = 0; r < 4; ++r) {
            gl_lds16(pA + (size_t)r * 32 * rsA + k0, lA + r * 2048);
            gl_lds16(pB + (size_t)r * 32 * rsB + k0, lB + r * 2048);
        }
        __syncthreads();
#pragma unroll
        for (int ks = 0; ks < 2; ++ks) {
            bf16x8 af[4], bfr[4];
#pragma unroll
            for (int t = 0; t < 4; ++t) {
                int gr_ = ((ks * 4 + quad) ^ l7) * 8;
                af[t]  = *(const bf16x8*)&As[(wm * 64 + t * 16 + l15) * 64 + gr_];
                bfr[t] = *(const bf16x8*)&Bs[(wn * 64 + t * 16 + l15) * 64 + gr_];
            }
#pragma unroll
            for (int mt = 0; mt < 4; ++mt)
#pragma unroll
                for (int nt = 0; nt < 4; ++nt)
                    acc[mt][nt] = __builtin_amdgcn_mfma_f32_16x16x32_bf16(
                        af[mt], bfr[nt], acc[mt][nt], 0, 0, 0);
        }
        __syncthreads();
    }

    float* ebw = (float*)smem + wave * (16 * ESTRIDE);
    int er = lane >> 4, ec4 = (lane & 15) * 4;
    int colb = bx * 128 + wn * 64;
    int rowb = by * 128 + wm * 64;
#pragma unroll
    for (int mt = 0; mt < 4; ++mt) {
#pragma unroll
        for (int nt = 0; nt < 4; ++nt) {
            f32x4 a = acc[mt][nt];
#pragma unroll
            for (int reg = 0; reg < 4; ++reg)
                ebw[(quad * 4 + reg) * ESTRIDE + nt * 16 + l15] = a[reg];
        }
#pragma unroll
        for (int j2 = 0; j2 < 4; ++j2) {
            int lr = er + 4 * j2;
            f32x2 v0 = *(f32x2*)&ebw[lr * ESTRIDE + ec4];
            f32x2 v1 = *(f32x2*)&ebw[lr * ESTRIDE + ec4 + 2];
            int gr = rowb + mt * 16 + lr;
            int gc = colb + ec4;
            size_t cidx = (size_t)b * bsC + (size_t)gr * rsC + gc;
            if (MODE == 1) {
                float bi = bias[gr];
                ushort4 st;
                st.x = f2bf(v0.x + bi); st.y = f2bf(v0.y + bi);
                st.z = f2bf(v1.x + bi); st.w = f2bf(v1.y + bi);
                *(ushort4*)&((u16*)Cv)[cidx] = st;
            } else {
                float bi = bias[gr];
                float4 xr = *(const float4*)&xres[cidx];
                float4 st = make_float4(v0.x + bi + xr.x, v0.y + bi + xr.y,
                                        v1.x + bi + xr.z, v1.y + bi + xr.w);
                *(float4*)&((float*)Cv)[cidx] = st;
            }
        }
    }
}

// ------------------------------------------------------------- flash attn
// Block: 64 q-rows x full d=512. 8 waves (512 thr). j-tiles of 128.
// q,k frags direct from global; P bf16 via LDS; V frags direct from global.
// No-max softmax: P=exp(S*scale), l accumulated in regs, O/l at end.
__global__ __launch_bounds__(512, 2) void flash_kernel(
        const u16* __restrict__ q, const u16* __restrict__ k,
        const u16* __restrict__ v, u16* __restrict__ O) {
    int iT = blockIdx.x, b = blockIdx.y;
    int i0 = iT * 64;
    const u16* qb = q + (size_t)b * 524288 + (size_t)i0 * 512;
    const u16* kb = k + (size_t)b * 524288;
    const u16* vb = v + (size_t)b * 524288;

    __shared__ __align__(16) char smem_raw[8 * 16 * ESTRIDE * 4];  // 33792 B
    __shared__ float lpart[256];
    __shared__ float lfull[64];
    u16* P = (u16*)smem_raw;

    int tid = threadIdx.x;
    int lane = tid & 63, wave = tid >> 6;          // wave 0..7
    int wm = wave >> 2, wn = wave & 3;             // QK slice: rows 32*wm, cols 32*wn
    int quad = lane >> 4, l15 = lane & 15;

    f32x4 accO[4][4];
#pragma unroll
    for (int mt = 0; mt < 4; ++mt)
#pragma unroll
        for (int nt = 0; nt < 4; ++nt)
            accO[mt][nt] = (f32x4){0.f, 0.f, 0.f, 0.f};
    float lsum[2][4];
#pragma unroll
    for (int mtl = 0; mtl < 2; ++mtl)
#pragma unroll
        for (int reg = 0; reg < 4; ++reg) lsum[mtl][reg] = 0.f;

    for (int j0 = 0; j0 < N_PIX; j0 += 128) {
        // ---- S slice 32x32 per wave: mt {2wm,2wm+1}, nt {2wn,2wn+1}
        f32x4 accS[2][2];
        accS[0][0] = accS[0][1] = accS[1][0] = accS[1][1] = (f32x4){0.f,0.f,0.f,0.f};
#pragma unroll
        for (int ks = 0; ks < 16; ++ks) {
            int ko = ks * 32 + quad * 8;
            bf16x8 aq0 = *(const bf16x8*)&qb[(size_t)((2*wm+0)*16 + l15) * 512 + ko];
            bf16x8 aq1 = *(const bf16x8*)&qb[(size_t)((2*wm+1)*16 + l15) * 512 + ko];
            bf16x8 bk0 = *(const bf16x8*)&kb[(size_t)(j0 + (2*wn+0)*16 + l15) * 512 + ko];
            bf16x8 bk1 = *(const bf16x8*)&kb[(size_t)(j0 + (2*wn+1)*16 + l15) * 512 + ko];
            accS[0][0] = __builtin_amdgcn_mfma_f32_16x16x32_bf16(aq0, bk0, accS[0][0], 0,0,0);
            accS[0][1] = __builtin_amdgcn_mfma_f32_16x16x32_bf16(aq0, bk1, accS[0][1], 0,0,0);
            accS[1][0] = __builtin_amdgcn_mfma_f32_16x16x32_bf16(aq1, bk0, accS[1][0], 0,0,0);
            accS[1][1] = __builtin_amdgcn_mfma_f32_16x16x32_bf16(aq1, bk1, accS[1][1], 0,0,0);
        }
        // ---- exp, accumulate row-sums, write P
#pragma unroll
        for (int mtl = 0; mtl < 2; ++mtl) {
            int prow = (2*wm + mtl) * 16 + quad * 4;
#pragma unroll
            for (int ntl = 0; ntl < 2; ++ntl) {
                int pcol = (2*wn + ntl) * 16 + l15;
#pragma unroll
                for (int reg = 0; reg < 4; ++reg) {
                    float p = __expf(accS[mtl][ntl][reg] * SCALE);
                    lsum[mtl][reg] += p;
                    P[(prow + reg) * PSTRIDE + pcol] = f2bf(p);
                }
            }
        }
        __syncthreads();
        // ---- O += P * V   (O slice per wave: all 64 rows, cols wave*64..+63)
#pragma unroll
        for (int ks = 0; ks < 4; ++ks) {
            int ko = ks * 32 + quad * 8;
            bf16x8 ap[4], bv4[4];
#pragma unroll
            for (int mt = 0; mt < 4; ++mt)
                ap[mt] = *(const bf16x8*)&P[(mt * 16 + l15) * PSTRIDE + ko];
#pragma unroll
            for (int nt = 0; nt < 4; ++nt)
                bv4[nt] = *(const bf16x8*)&vb[(size_t)(wave*64 + nt*16 + l15) * 1024 + j0 + ko];
#pragma unroll
            for (int mt = 0; mt < 4; ++mt)
#pragma unroll
                for (int nt = 0; nt < 4; ++nt)
                    accO[mt][nt] = __builtin_amdgcn_mfma_f32_16x16x32_bf16(
                        ap[mt], bv4[nt], accO[mt][nt], 0, 0, 0);
        }
        __syncthreads();
    }

    // ---- finalize l: reduce over 16 cols (shfl) then 4 wn waves (LDS)
#pragma unroll
    for (int mtl = 0; mtl < 2; ++mtl)
#pragma unroll
        for (int reg = 0; reg < 4; ++reg) {
            float s = lsum[mtl][reg];
            s += __shfl_xor(s, 1); s += __shfl_xor(s, 2);
            s += __shfl_xor(s, 4); s += __shfl_xor(s, 8);
            if (l15 == 0) {
                int row = (2*wm + mtl) * 16 + quad * 4 + reg;
                lpart[row * 4 + wn] = s;
            }
        }
    __syncthreads();
    if (tid < 64)
        lfull[tid] = lpart[tid*4] + lpart[tid*4+1] + lpart[tid*4+2] + lpart[tid*4+3];
    __syncthreads();

    // ---- epilogue: normalize, LDS transpose, vector store O[b][i][c]
    float* ebw = (float*)smem_raw + wave * (16 * ESTRIDE);
    int er = lane >> 4, ec4 = (lane & 15) * 4;
    u16* Ob = O + (size_t)b * 524288 + (size_t)i0 * 512;
#pragma unroll
    for (int mt = 0; mt < 4; ++mt) {
        float linv[4];
#pragma unroll
        for (int reg = 0; reg < 4; ++reg)
            linv[reg] = 1.0f / lfull[mt * 16 + quad * 4 + reg];
#pragma unroll
        for (int nt = 0; nt < 4; ++nt) {
            f32x4 a = accO[mt][nt];
#pragma unroll
            for (int reg = 0; reg < 4; ++reg)
                ebw[(quad * 4 + reg) * ESTRIDE + nt * 16 + l15] = a[reg] * linv[reg];
        }
#pragma unroll
        for (int j2 = 0; j2 < 4; ++j2) {
            int lr = er + 4 * j2;
            f32x2 v0 = *(f32x2*)&ebw[lr * ESTRIDE + ec4];
            f32x2 v1 = *(f32x2*)&ebw[lr * ESTRIDE + ec4 + 2];
            int gr = mt * 16 + lr;
            int gc = wave * 64 + ec4;
            ushort4 st;
            st.x = f2bf(v0.x); st.y = f2bf(v0.y);
            st.z = f2bf(v1.x); st.w = f2bf(v1.y);
            *(ushort4*)&Ob[(size_t)gr * 512 + gc] = st;
        }
    }
}

extern "C" void kernel_launch(void* const* d_in, const int* in_sizes, int n_in,
                              void* d_out, int out_size, void* d_ws, size_t ws_size,
                              hipStream_t stream) {
    const float* x    = (const float*)d_in[0];
    const float* gn_w = (const float*)d_in[1];
    const float* gn_b = (const float*)d_in[2];
    const float* wq   = (const float*)d_in[3];
    const float* bq   = (const float*)d_in[4];
    const float* wk   = (const float*)d_in[5];
    const float* bk   = (const float*)d_in[6];
    const float* wv   = (const float*)d_in[7];
    const float* bv   = (const float*)d_in[8];
    const float* wp   = (const float*)d_in[9];
    const float* bp   = (const float*)d_in[10];
    float* y = (float*)d_out;

    const size_t BCN = (size_t)BATCH * C_DIM * N_PIX;
    char* w = (char*)d_ws;
    u16* h  = (u16*)(w);
    u16* q  = (u16*)(w + 2 * BCN);
    u16* k  = (u16*)(w + 4 * BCN);
    u16* v  = (u16*)(w + 6 * BCN);
    u16* O  = (u16*)(w + 8 * BCN);
    u16* wb = (u16*)(w + 10 * BCN);            // 2 MB bf16 weights
    u16* wvb = wb + 524288, *wpb = wb + 786432;

    const long long BS = 524288;               // per-batch elems

    wconv_kernel<<<1024, 256, 0, stream>>>(wq, wk, wv, wp, wb);
    gn_kernel<<<1024, 256, 0, stream>>>(x, gn_w, gn_b, h);

    // q,k[n][o] merged, shared h staging  M=1024 N=512 K=512
    qk_kernel<<<dim3(4, 8, 32), 256, 0, stream>>>(h, wb, bq, bk, q, k);
    // v[c][n] = wv[c][c']*h[n][c'] + bv[c]  M=512 N=1024 K=512
    gemm_kernel<1><<<dim3(8, 4, 32), 256, 0, stream>>>(
        wvb, h, v, bv, nullptr, 512, 512, 512, 1024, 0, BS, BS);

    // fused attention: O[b][i][c]
    flash_kernel<<<dim3(16, 32), 512, 0, stream>>>(q, k, v, O);

    // y[o][n] = x + bp[o] + wp[o][c]*O[n][c]  M=512 N=1024 K=512
    gemm_kernel<4><<<dim3(8, 4, 32), 256, 0, stream>>>(
        wpb, O, y, bp, x, 512, 512, 512, 1024, 0, BS, BS);
}